// Round 1
// baseline (110.773 us; speedup 1.0000x reference)
//
#include <hip/hip_runtime.h>

#define TPB 256

// bit-reverse 7 bits
__device__ __forceinline__ int br7(int k) {
  return (int)(__brev((unsigned int)k) >> 25);
}

// 16-point in-register radix-2 DIT FFT, sign +.
// Input must be loaded in bit-reversed order; output natural order:
// out[k] = sum_j in[j] e^{+2 pi i j k / 16}
__device__ __forceinline__ void fft16_pos(float* ar, float* ai) {
  constexpr float TC[4][8] = {
    {1.f, 0.f, 0.f, 0.f, 0.f, 0.f, 0.f, 0.f},
    {1.f, 0.f, 0.f, 0.f, 0.f, 0.f, 0.f, 0.f},
    {1.f, 0.70710678f, 0.f, -0.70710678f, 0.f, 0.f, 0.f, 0.f},
    {1.f, 0.92387953f, 0.70710678f, 0.38268343f, 0.f, -0.38268343f, -0.70710678f, -0.92387953f}
  };
  constexpr float TS[4][8] = {
    {0.f, 0.f, 0.f, 0.f, 0.f, 0.f, 0.f, 0.f},
    {0.f, 1.f, 0.f, 0.f, 0.f, 0.f, 0.f, 0.f},
    {0.f, 0.70710678f, 1.f, 0.70710678f, 0.f, 0.f, 0.f, 0.f},
    {0.f, 0.38268343f, 0.70710678f, 0.92387953f, 1.f, 0.92387953f, 0.70710678f, 0.38268343f}
  };
  #pragma unroll
  for (int s = 0; s < 4; ++s) {
    const int L = 1 << s;
    #pragma unroll
    for (int jj = 0; jj < 8; ++jj) {
      if (jj < L) {
        const float tc = TC[s][jj], ts = TS[s][jj];
        #pragma unroll
        for (int i0 = jj; i0 < 16; i0 += 2 * L) {
          const float xr = ar[i0 + L], xi = ai[i0 + L];
          const float pr = xr * tc - xi * ts;
          const float pi = xr * ts + xi * tc;
          const float qr = ar[i0], qi = ai[i0];
          ar[i0 + L] = qr - pr; ai[i0 + L] = qi - pi;
          ar[i0]     = qr + pr; ai[i0]     = qi + pi;
        }
      }
    }
  }
}

// Forward transform of one [256 w][128 c] fp32 slab:
// produces Xfull[f][k] = sum_w sum_c src[w,c] e^{-2pi i (f w/256 + c k/128)}
// for f = 0..16 (negative f via Hermitian symmetry), all k = 0..127,
// stored BIT-REVERSED along k in XR/XI (position p holds k = br7(p)).
__device__ void forward_slab(const float* __restrict__ src,
                             float (*XR)[128], float (*XI)[128],
                             const float* Rc, const float* Rs, int tid) {
  const int c = tid & 127;
  const int half = tid >> 7;

  constexpr float C16[16] = {1.f, 0.92387953f, 0.70710678f, 0.38268343f, 0.f,
                             -0.38268343f, -0.70710678f, -0.92387953f, -1.f,
                             -0.92387953f, -0.70710678f, -0.38268343f, 0.f,
                             0.38268343f, 0.70710678f, 0.92387953f};
  constexpr float S16[16] = {0.f, 0.38268343f, 0.70710678f, 0.92387953f, 1.f,
                             0.92387953f, 0.70710678f, 0.38268343f, 0.f,
                             -0.38268343f, -0.70710678f, -0.92387953f, -1.f,
                             -0.92387953f, -0.70710678f, -0.38268343f};

  float accR[17], accI[17];
  #pragma unroll
  for (int f = 0; f < 17; ++f) { accR[f] = 0.f; accI[f] = 0.f; }

  // W-direction partial DFT, radix-16 split: w = 16*w1 + w0
  #pragma unroll 2
  for (int j = 0; j < 8; ++j) {
    const int w0 = half * 8 + j;
    float xv[16];
    #pragma unroll
    for (int w1 = 0; w1 < 16; ++w1)
      xv[w1] = src[(w1 * 16 + w0) * 128 + c];
    // real-input DFT-16 over w1 (Hermitian: keep g=0..8), literal twiddles
    float SRe[9], SIm[9];
    #pragma unroll
    for (int g = 0; g < 9; ++g) {
      float sr = 0.f, si = 0.f;
      #pragma unroll
      for (int w1 = 0; w1 < 16; ++w1) {
        const int m = (g * w1) & 15;
        sr = fmaf(xv[w1], C16[m], sr);
        si = fmaf(xv[w1], -S16[m], si);
      }
      SRe[g] = sr; SIm[g] = si;
    }
    // combine with e^{-2 pi i f w0/256}
    #pragma unroll
    for (int f = 0; f < 17; ++f) {
      const int g = f & 15;
      const float sr = (g <= 8) ? SRe[g] : SRe[16 - g];
      const float si = (g <= 8) ? SIm[g] : -SIm[16 - g];
      const int idx = (f * w0) & 255;
      const float tc = Rc[idx], ts = -Rs[idx];
      accR[f] = fmaf(sr, tc, fmaf(-si, ts, accR[f]));
      accI[f] = fmaf(sr, ts, fmaf(si, tc, accI[f]));
    }
  }
  // cross-half reduction into LDS
  if (half == 0) {
    #pragma unroll
    for (int f = 0; f < 17; ++f) { XR[f][c] = accR[f]; XI[f][c] = accI[f]; }
  }
  __syncthreads();
  if (half == 1) {
    #pragma unroll
    for (int f = 0; f < 17; ++f) { XR[f][c] += accR[f]; XI[f][c] += accI[f]; }
  }
  __syncthreads();

  // 128-pt DIF FFT along c for 17 rows (natural in -> bit-reversed out), sign -
  for (int s = 6; s >= 0; --s) {
    const int L = 1 << s;
    for (int u = tid; u < 17 * 64; u += TPB) {
      const int row = u >> 6, qq = u & 63;
      const int jj = qq & (L - 1);
      const int pos = ((qq >> s) << (s + 1)) | jj;
      const int ti = jj << (7 - s);
      const float tc = Rc[ti], ts = Rs[ti];
      const float a0r = XR[row][pos],     a0i = XI[row][pos];
      const float b0r = XR[row][pos + L], b0i = XI[row][pos + L];
      XR[row][pos] = a0r + b0r; XI[row][pos] = a0i + b0i;
      const float dr = a0r - b0r, di = a0i - b0i;
      XR[row][pos + L] = fmaf(dr, tc, di * ts);   // (dr+i di)*(tc - i ts)
      XI[row][pos + L] = fmaf(di, tc, -dr * ts);
    }
    __syncthreads();
  }
}

// K1: precompute w_ft / b_ft spectra for the 32 active h rows.
__global__ __launch_bounds__(TPB) void precompute_wb_ft(
    const float* __restrict__ wp, const float* __restrict__ bp,
    float2* __restrict__ wsW, float2* __restrict__ wsB) {
  __shared__ float XR[17][128], XI[17][128];
  __shared__ float Rc[256], Rs[256];
  const int tid = threadIdx.x;
  { float sv, cv; sincosf(6.283185307179586f * (float)tid / 256.0f, &sv, &cv);
    Rc[tid] = cv; Rs[tid] = sv; }
  __syncthreads();
  const int which = blockIdx.x >> 5;   // 0 = w, 1 = b
  const int ha = blockIdx.x & 31;
  const int h = (ha < 16) ? ha : (224 + ha);
  const float* src = (which ? bp : wp) + (size_t)h * 32768;
  forward_slab(src, XR, XI, Rc, Rs, tid);
  float2* dst = which ? wsB : wsW;
  for (int u = tid; u < 32 * 65; u += TPB) {
    const int fi = u / 65, k = u - fi * 65;
    const int f = fi - 16;
    float xr, xi;
    if (f >= 0) { const int p = br7(k); xr = XR[f][p]; xi = XI[f][p]; }
    else { const int kk = (128 - k) & 127; const int p = br7(kk);
           xr = XR[-f][p]; xi = -XI[-f][p]; }
    dst[(ha * 32 + fi) * 65 + k] = make_float2(xr, xi);
  }
}

// K2: bid<256 -> active slab full pipeline; bid>=256 -> zero-fill inactive slab.
__global__ __launch_bounds__(TPB) void fourier_main(
    const float* __restrict__ x, const float2* __restrict__ wsW,
    const float2* __restrict__ wsB, float* __restrict__ out) {
  const int bid = blockIdx.x;
  const int tid = threadIdx.x;
  if (bid >= 256) {
    const int zi = bid - 256;
    const int zb = zi / 224;
    const int zh = 16 + (zi - zb * 224);
    float4* o4 = (float4*)(out + ((size_t)(zb * 256 + zh)) * 32768);
    const float4 z = make_float4(0.f, 0.f, 0.f, 0.f);
    for (int i = tid; i < 8192; i += TPB) o4[i] = z;
    return;
  }
  __shared__ float XR[17][128], XI[17][128];
  __shared__ float TR[32][128], TI[32][128];
  __shared__ float Rc[256], Rs[256];
  { float sv, cv; sincosf(6.283185307179586f * (float)tid / 256.0f, &sv, &cv);
    Rc[tid] = cv; Rs[tid] = sv; }
  __syncthreads();

  const int b = bid >> 5;
  const int ha = bid & 31;
  const int h = (ha < 16) ? ha : (224 + ha);
  const float* src = x + ((size_t)(b * 256 + h)) * 32768;
  forward_slab(src, XR, XI, Rc, Rs, tid);

  // phase C: Z = X*Wft + Bft, apply irfft alpha weights, zero k>64,
  // store bit-reversed along k into TR/TI (ready for DIT).
  for (int u = tid; u < 32 * 128; u += TPB) {
    const int fi = u >> 7, k = u & 127;
    float gr = 0.f, gi = 0.f;
    if (k <= 64) {
      const int f = fi - 16;
      float xr, xi;
      if (f >= 0) { const int p = br7(k); xr = XR[f][p]; xi = XI[f][p]; }
      else { const int kk = (128 - k) & 127; const int p = br7(kk);
             xr = XR[-f][p]; xi = -XI[-f][p]; }
      const float2 wf = wsW[(ha * 32 + fi) * 65 + k];
      const float2 bf = wsB[(ha * 32 + fi) * 65 + k];
      gr = xr * wf.x - xi * wf.y + bf.x;
      gi = xr * wf.y + xi * wf.x + bf.y;
      const float al = (k == 0 || k == 64) ? 1.f : 2.f;
      gr *= al; gi *= al;
    }
    const int p = br7(k);
    TR[fi][p] = gr; TI[fi][p] = gi;
  }
  __syncthreads();

  // phase D: t[f,c] = sum_k G[f,k] e^{+2 pi i k c/128}; 32 rows, DIT sign +.
  for (int s = 0; s <= 6; ++s) {
    const int L = 1 << s;
    for (int u = tid; u < 32 * 64; u += TPB) {
      const int row = u >> 6, qq = u & 63;
      const int jj = qq & (L - 1);
      const int pos = ((qq >> s) << (s + 1)) | jj;
      const int ti = jj << (7 - s);
      const float tc = Rc[ti], ts = Rs[ti];
      const float b0r = TR[row][pos + L], b0i = TI[row][pos + L];
      const float pr = b0r * tc - b0i * ts;
      const float pi = fmaf(b0r, ts, b0i * tc);
      const float a0r = TR[row][pos], a0i = TI[row][pos];
      TR[row][pos + L] = a0r - pr; TI[row][pos + L] = a0i - pi;
      TR[row][pos]     = a0r + pr; TI[row][pos]     = a0i + pi;
    }
    __syncthreads();
  }

  // phase E: out[16*w1+w0, c] = (1/32768) * Re( sum_g U[g] e^{+2pi i g w1/16} ),
  //          U[g] = t[g,c] e^{+2pi i g w0/256} + t[g-16,c] e^{+2pi i (g-16) w0/256}
  const int c = tid & 127;
  const int q = tid >> 7;
  constexpr int BR4[16] = {0, 8, 4, 12, 2, 10, 6, 14, 1, 9, 5, 13, 3, 11, 7, 15};
  const float inv = 1.0f / 32768.0f;
  float* og = out + ((size_t)(b * 256 + h)) * 32768;

  float tre[32], tim[32];
  #pragma unroll
  for (int fi = 0; fi < 32; ++fi) { tre[fi] = TR[fi][c]; tim[fi] = TI[fi][c]; }

  #pragma unroll 1
  for (int it = 0; it < 8; ++it) {
    const int w0 = q + it * 2;
    float Ur[16], Ui[16];
    #pragma unroll
    for (int g = 0; g < 16; ++g) {
      const int gb = BR4[g];            // load bit-reversed for DIT
      const float t1r = tre[gb + 16], t1i = tim[gb + 16];  // f = gb   (fi=f+16)
      const float t0r = tre[gb],      t0i = tim[gb];       // f = gb-16
      const int i1 = (gb * w0) & 255;
      const int i2 = ((gb - 16) * w0) & 255;
      const float c1 = Rc[i1], s1 = Rs[i1];   // e^{+i theta}
      const float c2 = Rc[i2], s2 = Rs[i2];
      Ur[g] = t1r * c1 - t1i * s1 + t0r * c2 - t0i * s2;
      Ui[g] = t1r * s1 + t1i * c1 + t0r * s2 + t0i * c2;
    }
    fft16_pos(Ur, Ui);
    #pragma unroll
    for (int w1 = 0; w1 < 16; ++w1)
      og[(w1 * 16 + w0) * 128 + c] = Ur[w1] * inv;
  }
}

extern "C" void kernel_launch(void* const* d_in, const int* in_sizes, int n_in,
                              void* d_out, int out_size, void* d_ws, size_t ws_size,
                              hipStream_t stream) {
  const float* x = (const float*)d_in[0];
  const float* w = (const float*)d_in[1];
  const float* b = (const float*)d_in[2];
  float* out = (float*)d_out;
  float2* wsW = (float2*)d_ws;
  float2* wsB = wsW + 32 * 32 * 65;   // 66560 float2 each (532,480 B)

  hipLaunchKernelGGL(precompute_wb_ft, dim3(64), dim3(TPB), 0, stream,
                     w, b, wsW, wsB);
  hipLaunchKernelGGL(fourier_main, dim3(2048), dim3(TPB), 0, stream,
                     x, wsW, wsB, out);
}

// Round 2
// 92.558 us; speedup vs baseline: 1.1968x; 1.1968x over previous
//
#include <hip/hip_runtime.h>

#define TPB 512

// bit-reverse 7 bits
__device__ __forceinline__ int br7(int k) {
  return (int)(__brev((unsigned int)k) >> 25);
}

// 16-point in-register radix-2 DIT FFT, sign +.
// Input must be loaded in bit-reversed order; output natural order:
// out[k] = sum_j in[j] e^{+2 pi i j k / 16}
__device__ __forceinline__ void fft16_pos(float* ar, float* ai) {
  constexpr float TC[4][8] = {
    {1.f, 0.f, 0.f, 0.f, 0.f, 0.f, 0.f, 0.f},
    {1.f, 0.f, 0.f, 0.f, 0.f, 0.f, 0.f, 0.f},
    {1.f, 0.70710678f, 0.f, -0.70710678f, 0.f, 0.f, 0.f, 0.f},
    {1.f, 0.92387953f, 0.70710678f, 0.38268343f, 0.f, -0.38268343f, -0.70710678f, -0.92387953f}
  };
  constexpr float TS[4][8] = {
    {0.f, 0.f, 0.f, 0.f, 0.f, 0.f, 0.f, 0.f},
    {0.f, 1.f, 0.f, 0.f, 0.f, 0.f, 0.f, 0.f},
    {0.f, 0.70710678f, 1.f, 0.70710678f, 0.f, 0.f, 0.f, 0.f},
    {0.f, 0.38268343f, 0.70710678f, 0.92387953f, 1.f, 0.92387953f, 0.70710678f, 0.38268343f}
  };
  #pragma unroll
  for (int s = 0; s < 4; ++s) {
    const int L = 1 << s;
    #pragma unroll
    for (int jj = 0; jj < 8; ++jj) {
      if (jj < L) {
        const float tc = TC[s][jj], ts = TS[s][jj];
        #pragma unroll
        for (int i0 = jj; i0 < 16; i0 += 2 * L) {
          const float xr = ar[i0 + L], xi = ai[i0 + L];
          const float pr = xr * tc - xi * ts;
          const float pi = xr * ts + xi * tc;
          const float qr = ar[i0], qi = ai[i0];
          ar[i0 + L] = qr - pr; ai[i0 + L] = qi - pi;
          ar[i0]     = qr + pr; ai[i0]     = qi + pi;
        }
      }
    }
  }
}

// Forward transform of one [256 w][128 c] fp32 slab with 512 threads:
// produces Xfull[f][k] = sum_w sum_c src[w,c] e^{-2pi i (f w/256 + c k/128)}
// for f = 0..16 (negative f via Hermitian symmetry), all k = 0..127,
// stored BIT-REVERSED along k in XR/XI (position p holds k = br7(p)).
// SR/SI are [17][128] LDS scratch (may alias buffers unused until after
// the final barrier inside this function).
__device__ void forward_slab(const float* __restrict__ src,
                             float (*XR)[128], float (*XI)[128],
                             float (*SR)[128], float (*SI)[128],
                             const float* Rc, const float* Rs, int tid) {
  const int c = tid & 127;
  const int q4 = tid >> 7;   // 0..3

  constexpr float C16[16] = {1.f, 0.92387953f, 0.70710678f, 0.38268343f, 0.f,
                             -0.38268343f, -0.70710678f, -0.92387953f, -1.f,
                             -0.92387953f, -0.70710678f, -0.38268343f, 0.f,
                             0.38268343f, 0.70710678f, 0.92387953f};
  constexpr float S16[16] = {0.f, 0.38268343f, 0.70710678f, 0.92387953f, 1.f,
                             0.92387953f, 0.70710678f, 0.38268343f, 0.f,
                             -0.38268343f, -0.70710678f, -0.92387953f, -1.f,
                             -0.92387953f, -0.70710678f, -0.38268343f};

  float accR[17], accI[17];
  #pragma unroll
  for (int f = 0; f < 17; ++f) { accR[f] = 0.f; accI[f] = 0.f; }

  // W-direction partial DFT, radix-16 split: w = 16*w1 + w0; this thread
  // handles w0 = q4*4 + j for j = 0..3.
  #pragma unroll 2
  for (int j = 0; j < 4; ++j) {
    const int w0 = q4 * 4 + j;
    float xv[16];
    #pragma unroll
    for (int w1 = 0; w1 < 16; ++w1)
      xv[w1] = src[(w1 * 16 + w0) * 128 + c];
    // real-input DFT-16 over w1 (Hermitian: keep g=0..8), literal twiddles
    float SRe[9], SIm[9];
    #pragma unroll
    for (int g = 0; g < 9; ++g) {
      float sr = 0.f, si = 0.f;
      #pragma unroll
      for (int w1 = 0; w1 < 16; ++w1) {
        const int m = (g * w1) & 15;
        sr = fmaf(xv[w1], C16[m], sr);
        si = fmaf(xv[w1], -S16[m], si);
      }
      SRe[g] = sr; SIm[g] = si;
    }
    // combine with e^{-2 pi i f w0/256}
    #pragma unroll
    for (int f = 0; f < 17; ++f) {
      const int g = f & 15;
      const float sr = (g <= 8) ? SRe[g] : SRe[16 - g];
      const float si = (g <= 8) ? SIm[g] : -SIm[16 - g];
      const int idx = (f * w0) & 255;
      const float tc = Rc[idx], ts = -Rs[idx];
      accR[f] = fmaf(sr, tc, fmaf(-si, ts, accR[f]));
      accI[f] = fmaf(sr, ts, fmaf(si, tc, accI[f]));
    }
  }
  // 4-way cross-quarter reduction: q0/q2 -> XR/XI, q1/q3 -> SR/SI, then merge.
  if (q4 == 0) {
    #pragma unroll
    for (int f = 0; f < 17; ++f) { XR[f][c] = accR[f]; XI[f][c] = accI[f]; }
  } else if (q4 == 1) {
    #pragma unroll
    for (int f = 0; f < 17; ++f) { SR[f][c] = accR[f]; SI[f][c] = accI[f]; }
  }
  __syncthreads();
  if (q4 == 2) {
    #pragma unroll
    for (int f = 0; f < 17; ++f) { XR[f][c] += accR[f]; XI[f][c] += accI[f]; }
  } else if (q4 == 3) {
    #pragma unroll
    for (int f = 0; f < 17; ++f) { SR[f][c] += accR[f]; SI[f][c] += accI[f]; }
  }
  __syncthreads();
  for (int u = tid; u < 17 * 128; u += TPB) {
    const int row = u >> 7, cc = u & 127;
    XR[row][cc] += SR[row][cc];
    XI[row][cc] += SI[row][cc];
  }
  __syncthreads();

  // 128-pt DIF FFT along c for 17 rows (natural in -> bit-reversed out), sign -
  for (int s = 6; s >= 0; --s) {
    const int L = 1 << s;
    for (int u = tid; u < 17 * 64; u += TPB) {
      const int row = u >> 6, qq = u & 63;
      const int jj = qq & (L - 1);
      const int pos = ((qq >> s) << (s + 1)) | jj;
      const int ti = jj << (7 - s);
      const float tc = Rc[ti], ts = Rs[ti];
      const float a0r = XR[row][pos],     a0i = XI[row][pos];
      const float b0r = XR[row][pos + L], b0i = XI[row][pos + L];
      XR[row][pos] = a0r + b0r; XI[row][pos] = a0i + b0i;
      const float dr = a0r - b0r, di = a0i - b0i;
      XR[row][pos + L] = fmaf(dr, tc, di * ts);   // (dr+i di)*(tc - i ts)
      XI[row][pos + L] = fmaf(di, tc, -dr * ts);
    }
    __syncthreads();
  }
}

// K1: precompute w_ft / b_ft spectra for the 32 active h rows.
__global__ __launch_bounds__(TPB) void precompute_wb_ft(
    const float* __restrict__ wp, const float* __restrict__ bp,
    float2* __restrict__ wsW, float2* __restrict__ wsB) {
  __shared__ float XR[17][128], XI[17][128];
  __shared__ float SR[17][128], SI[17][128];
  __shared__ float Rc[256], Rs[256];
  const int tid = threadIdx.x;
  for (int i = tid; i < 256; i += TPB) {
    float sv, cv; sincosf(6.283185307179586f * (float)i / 256.0f, &sv, &cv);
    Rc[i] = cv; Rs[i] = sv;
  }
  __syncthreads();
  const int which = blockIdx.x >> 5;   // 0 = w, 1 = b
  const int ha = blockIdx.x & 31;
  const int h = (ha < 16) ? ha : (224 + ha);
  const float* src = (which ? bp : wp) + (size_t)h * 32768;
  forward_slab(src, XR, XI, SR, SI, Rc, Rs, tid);
  float2* dst = which ? wsB : wsW;
  for (int u = tid; u < 32 * 65; u += TPB) {
    const int fi = u / 65, k = u - fi * 65;
    const int f = fi - 16;
    float xr, xi;
    if (f >= 0) { const int p = br7(k); xr = XR[f][p]; xi = XI[f][p]; }
    else { const int kk = (128 - k) & 127; const int p = br7(kk);
           xr = XR[-f][p]; xi = -XI[-f][p]; }
    dst[(ha * 32 + fi) * 65 + k] = make_float2(xr, xi);
  }
}

// K2: bid<256 -> active slab full pipeline; bid>=256 -> zero-fill inactive slab.
__global__ __launch_bounds__(TPB) void fourier_main(
    const float* __restrict__ x, const float2* __restrict__ wsW,
    const float2* __restrict__ wsB, float* __restrict__ out) {
  const int bid = blockIdx.x;
  const int tid = threadIdx.x;
  if (bid >= 256) {
    const int zi = bid - 256;
    const int zb = zi / 224;
    const int zh = 16 + (zi - zb * 224);
    float4* o4 = (float4*)(out + ((size_t)(zb * 256 + zh)) * 32768);
    const float4 z = make_float4(0.f, 0.f, 0.f, 0.f);
    for (int i = tid; i < 8192; i += TPB) o4[i] = z;
    return;
  }
  __shared__ float XR[17][128], XI[17][128];
  __shared__ float TR[32][128], TI[32][128];
  __shared__ float Rc[256], Rs[256];
  for (int i = tid; i < 256; i += TPB) {
    float sv, cv; sincosf(6.283185307179586f * (float)i / 256.0f, &sv, &cv);
    Rc[i] = cv; Rs[i] = sv;
  }
  __syncthreads();

  const int b = bid >> 5;
  const int ha = bid & 31;
  const int h = (ha < 16) ? ha : (224 + ha);
  const float* src = x + ((size_t)(b * 256 + h)) * 32768;
  // TR/TI rows 0..16 double as the forward reduction scratch.
  forward_slab(src, XR, XI, (float(*)[128])TR, (float(*)[128])TI, Rc, Rs, tid);

  // phase C: Z = X*Wft + Bft, apply irfft alpha weights, zero k>64,
  // store bit-reversed along k into TR/TI (ready for DIT).
  for (int u = tid; u < 32 * 128; u += TPB) {
    const int fi = u >> 7, k = u & 127;
    float gr = 0.f, gi = 0.f;
    if (k <= 64) {
      const int f = fi - 16;
      float xr, xi;
      if (f >= 0) { const int p = br7(k); xr = XR[f][p]; xi = XI[f][p]; }
      else { const int kk = (128 - k) & 127; const int p = br7(kk);
             xr = XR[-f][p]; xi = -XI[-f][p]; }
      const float2 wf = wsW[(ha * 32 + fi) * 65 + k];
      const float2 bf = wsB[(ha * 32 + fi) * 65 + k];
      gr = xr * wf.x - xi * wf.y + bf.x;
      gi = xr * wf.y + xi * wf.x + bf.y;
      const float al = (k == 0 || k == 64) ? 1.f : 2.f;
      gr *= al; gi *= al;
    }
    const int p = br7(k);
    TR[fi][p] = gr; TI[fi][p] = gi;
  }
  __syncthreads();

  // phase D: t[f,c] = sum_k G[f,k] e^{+2 pi i k c/128}; 32 rows, DIT sign +.
  for (int s = 0; s <= 6; ++s) {
    const int L = 1 << s;
    for (int u = tid; u < 32 * 64; u += TPB) {
      const int row = u >> 6, qq = u & 63;
      const int jj = qq & (L - 1);
      const int pos = ((qq >> s) << (s + 1)) | jj;
      const int ti = jj << (7 - s);
      const float tc = Rc[ti], ts = Rs[ti];
      const float b0r = TR[row][pos + L], b0i = TI[row][pos + L];
      const float pr = b0r * tc - b0i * ts;
      const float pi = fmaf(b0r, ts, b0i * tc);
      const float a0r = TR[row][pos], a0i = TI[row][pos];
      TR[row][pos + L] = a0r - pr; TI[row][pos + L] = a0i - pi;
      TR[row][pos]     = a0r + pr; TI[row][pos]     = a0i + pi;
    }
    __syncthreads();
  }

  // phase E: out[16*w1+w0, c] = (1/32768) * Re( sum_g U[g] e^{+2pi i g w1/16} ),
  //          U[g] = t[g,c] e^{+2pi i g w0/256} + t[g-16,c] e^{+2pi i (g-16) w0/256}
  const int c = tid & 127;
  const int q = tid >> 7;          // 0..3
  constexpr int BR4[16] = {0, 8, 4, 12, 2, 10, 6, 14, 1, 9, 5, 13, 3, 11, 7, 15};
  const float inv = 1.0f / 32768.0f;
  float* og = out + ((size_t)(b * 256 + h)) * 32768;

  #pragma unroll 1
  for (int it = 0; it < 4; ++it) {
    const int w0 = q + it * 4;     // wave-uniform
    float Ur[16], Ui[16];
    #pragma unroll
    for (int g = 0; g < 16; ++g) {
      const int gb = BR4[g];            // load bit-reversed for DIT
      const float t1r = TR[gb + 16][c], t1i = TI[gb + 16][c];  // f = gb
      const float t0r = TR[gb][c],      t0i = TI[gb][c];       // f = gb-16
      const int i1 = (gb * w0) & 255;
      const int i2 = ((gb - 16) * w0) & 255;
      const float c1 = Rc[i1], s1 = Rs[i1];   // e^{+i theta}
      const float c2 = Rc[i2], s2 = Rs[i2];
      Ur[g] = t1r * c1 - t1i * s1 + t0r * c2 - t0i * s2;
      Ui[g] = t1r * s1 + t1i * c1 + t0r * s2 + t0i * c2;
    }
    fft16_pos(Ur, Ui);
    #pragma unroll
    for (int w1 = 0; w1 < 16; ++w1)
      og[(w1 * 16 + w0) * 128 + c] = Ur[w1] * inv;
  }
}

extern "C" void kernel_launch(void* const* d_in, const int* in_sizes, int n_in,
                              void* d_out, int out_size, void* d_ws, size_t ws_size,
                              hipStream_t stream) {
  const float* x = (const float*)d_in[0];
  const float* w = (const float*)d_in[1];
  const float* b = (const float*)d_in[2];
  float* out = (float*)d_out;
  float2* wsW = (float2*)d_ws;
  float2* wsB = wsW + 32 * 32 * 65;   // 66560 float2 each (532,480 B)

  hipLaunchKernelGGL(precompute_wb_ft, dim3(64), dim3(TPB), 0, stream,
                     w, b, wsW, wsB);
  hipLaunchKernelGGL(fourier_main, dim3(2048), dim3(TPB), 0, stream,
                     x, wsW, wsB, out);
}

// Round 4
// 76.363 us; speedup vs baseline: 1.4506x; 1.2121x over previous
//
#include <hip/hip_runtime.h>

#define TPB 512
#define NF0 1056   // fill slabs handled by K0
#define NF2 736    // fill slabs handled by K2 (NF0+NF2 == 8*224 == 1792)

typedef float f4v __attribute__((ext_vector_type(4)));

// bit-reverse 7 bits
__device__ __forceinline__ int br7(int k) {
  return (int)(__brev((unsigned int)k) >> 25);
}

__device__ __forceinline__ void zero_fill_slab(float* __restrict__ out,
                                               int zi, int tid) {
  const int zb = zi / 224;
  const int zh = 16 + (zi - zb * 224);
  f4v* o4 = (f4v*)(out + ((size_t)(zb * 256 + zh)) * 32768);
  const f4v z = {0.f, 0.f, 0.f, 0.f};
  #pragma unroll 4
  for (int i = tid; i < 8192; i += TPB)
    __builtin_nontemporal_store(z, &o4[i]);
}

// 16-point in-register radix-2 DIT FFT, sign +.
// Input in bit-reversed order; output natural: out[k] = sum_j in[j] e^{+2pi i jk/16}
__device__ __forceinline__ void fft16_pos(float* ar, float* ai) {
  constexpr float TC[4][8] = {
    {1.f, 0.f, 0.f, 0.f, 0.f, 0.f, 0.f, 0.f},
    {1.f, 0.f, 0.f, 0.f, 0.f, 0.f, 0.f, 0.f},
    {1.f, 0.70710678f, 0.f, -0.70710678f, 0.f, 0.f, 0.f, 0.f},
    {1.f, 0.92387953f, 0.70710678f, 0.38268343f, 0.f, -0.38268343f, -0.70710678f, -0.92387953f}
  };
  constexpr float TS[4][8] = {
    {0.f, 0.f, 0.f, 0.f, 0.f, 0.f, 0.f, 0.f},
    {0.f, 1.f, 0.f, 0.f, 0.f, 0.f, 0.f, 0.f},
    {0.f, 0.70710678f, 1.f, 0.70710678f, 0.f, 0.f, 0.f, 0.f},
    {0.f, 0.38268343f, 0.70710678f, 0.92387953f, 1.f, 0.92387953f, 0.70710678f, 0.38268343f}
  };
  #pragma unroll
  for (int s = 0; s < 4; ++s) {
    const int L = 1 << s;
    #pragma unroll
    for (int jj = 0; jj < 8; ++jj) {
      if (jj < L) {
        const float tc = TC[s][jj], ts = TS[s][jj];
        #pragma unroll
        for (int i0 = jj; i0 < 16; i0 += 2 * L) {
          const float xr = ar[i0 + L], xi = ai[i0 + L];
          const float pr = xr * tc - xi * ts;
          const float pi = xr * ts + xi * tc;
          const float qr = ar[i0], qi = ai[i0];
          ar[i0 + L] = qr - pr; ai[i0 + L] = qi - pi;
          ar[i0]     = qr + pr; ai[i0]     = qi + pi;
        }
      }
    }
  }
}

// Forward transform of one [256 w][128 c] fp32 slab with 512 threads:
// Xfull[f][k] = sum_w sum_c src[w,c] e^{-2pi i (f w/256 + c k/128)}, f=0..16,
// stored BIT-REVERSED along k in XR/XI. SR/SI: [17][128] scratch.
__device__ void forward_slab(const float* __restrict__ src,
                             float (*XR)[128], float (*XI)[128],
                             float (*SR)[128], float (*SI)[128],
                             const float* Rc, const float* Rs, int tid) {
  const int c = tid & 127;
  const int q4 = tid >> 7;   // 0..3

  constexpr float C16[16] = {1.f, 0.92387953f, 0.70710678f, 0.38268343f, 0.f,
                             -0.38268343f, -0.70710678f, -0.92387953f, -1.f,
                             -0.92387953f, -0.70710678f, -0.38268343f, 0.f,
                             0.38268343f, 0.70710678f, 0.92387953f};
  constexpr float S16[16] = {0.f, 0.38268343f, 0.70710678f, 0.92387953f, 1.f,
                             0.92387953f, 0.70710678f, 0.38268343f, 0.f,
                             -0.38268343f, -0.70710678f, -0.92387953f, -1.f,
                             -0.92387953f, -0.70710678f, -0.38268343f};

  float accR[17], accI[17];
  #pragma unroll
  for (int f = 0; f < 17; ++f) { accR[f] = 0.f; accI[f] = 0.f; }

  #pragma unroll 2
  for (int j = 0; j < 4; ++j) {
    const int w0 = q4 * 4 + j;
    float xv[16];
    #pragma unroll
    for (int w1 = 0; w1 < 16; ++w1)
      xv[w1] = src[(w1 * 16 + w0) * 128 + c];
    float SRe[9], SIm[9];
    #pragma unroll
    for (int g = 0; g < 9; ++g) {
      float sr = 0.f, si = 0.f;
      #pragma unroll
      for (int w1 = 0; w1 < 16; ++w1) {
        const int m = (g * w1) & 15;
        sr = fmaf(xv[w1], C16[m], sr);
        si = fmaf(xv[w1], -S16[m], si);
      }
      SRe[g] = sr; SIm[g] = si;
    }
    #pragma unroll
    for (int f = 0; f < 17; ++f) {
      const int g = f & 15;
      const float sr = (g <= 8) ? SRe[g] : SRe[16 - g];
      const float si = (g <= 8) ? SIm[g] : -SIm[16 - g];
      const int idx = (f * w0) & 255;
      const float tc = Rc[idx], ts = -Rs[idx];
      accR[f] = fmaf(sr, tc, fmaf(-si, ts, accR[f]));
      accI[f] = fmaf(sr, ts, fmaf(si, tc, accI[f]));
    }
  }
  if (q4 == 0) {
    #pragma unroll
    for (int f = 0; f < 17; ++f) { XR[f][c] = accR[f]; XI[f][c] = accI[f]; }
  } else if (q4 == 1) {
    #pragma unroll
    for (int f = 0; f < 17; ++f) { SR[f][c] = accR[f]; SI[f][c] = accI[f]; }
  }
  __syncthreads();
  if (q4 == 2) {
    #pragma unroll
    for (int f = 0; f < 17; ++f) { XR[f][c] += accR[f]; XI[f][c] += accI[f]; }
  } else if (q4 == 3) {
    #pragma unroll
    for (int f = 0; f < 17; ++f) { SR[f][c] += accR[f]; SI[f][c] += accI[f]; }
  }
  __syncthreads();
  for (int u = tid; u < 17 * 128; u += TPB) {
    const int row = u >> 7, cc = u & 127;
    XR[row][cc] += SR[row][cc];
    XI[row][cc] += SI[row][cc];
  }
  __syncthreads();

  // 128-pt DIF FFT along c for 17 rows (natural in -> bit-reversed out), sign -
  for (int s = 6; s >= 0; --s) {
    const int L = 1 << s;
    for (int u = tid; u < 17 * 64; u += TPB) {
      const int row = u >> 6, qq = u & 63;
      const int jj = qq & (L - 1);
      const int pos = ((qq >> s) << (s + 1)) | jj;
      const int ti = jj << (7 - s);
      const float tc = Rc[ti], ts = Rs[ti];
      const float a0r = XR[row][pos],     a0i = XI[row][pos];
      const float b0r = XR[row][pos + L], b0i = XI[row][pos + L];
      XR[row][pos] = a0r + b0r; XI[row][pos] = a0i + b0i;
      const float dr = a0r - b0r, di = a0i - b0i;
      XR[row][pos + L] = fmaf(dr, tc, di * ts);   // (dr+i di)*(tc - i ts)
      XI[row][pos + L] = fmaf(di, tc, -dr * ts);
    }
    __syncthreads();
  }
}

// K0: blocks 0..63 precompute w_ft/b_ft spectra; blocks 64.. zero-fill
// the first NF0 inactive output slabs (independent work to hide wft latency).
__global__ __launch_bounds__(TPB) void k0_wft_and_fill(
    const float* __restrict__ wp, const float* __restrict__ bp,
    float2* __restrict__ wsW, float2* __restrict__ wsB,
    float* __restrict__ out) {
  const int bid = blockIdx.x;
  const int tid = threadIdx.x;
  if (bid >= 64) {
    zero_fill_slab(out, bid - 64, tid);
    return;
  }
  __shared__ float XR[17][128], XI[17][128];
  __shared__ float SR[17][128], SI[17][128];
  __shared__ float Rc[256], Rs[256];
  for (int i = tid; i < 256; i += TPB) {
    float sv, cv; sincosf(6.283185307179586f * (float)i / 256.0f, &sv, &cv);
    Rc[i] = cv; Rs[i] = sv;
  }
  __syncthreads();
  const int which = bid >> 5;   // 0 = w, 1 = b
  const int ha = bid & 31;
  const int h = (ha < 16) ? ha : (224 + ha);
  const float* src = (which ? bp : wp) + (size_t)h * 32768;
  forward_slab(src, XR, XI, SR, SI, Rc, Rs, tid);
  float2* dst = which ? wsB : wsW;
  for (int u = tid; u < 32 * 65; u += TPB) {
    const int fi = u / 65, k = u - fi * 65;
    const int f = fi - 16;
    float xr, xi;
    if (f >= 0) { const int p = br7(k); xr = XR[f][p]; xi = XI[f][p]; }
    else { const int kk = (128 - k) & 127; const int p = br7(kk);
           xr = XR[-f][p]; xi = -XI[-f][p]; }
    dst[(ha * 32 + fi) * 65 + k] = make_float2(xr, xi);
  }
}

// K2: blocks 0..255 active slab pipeline; blocks 256.. fill remaining slabs.
__global__ __launch_bounds__(TPB) void fourier_active(
    const float* __restrict__ x, const float2* __restrict__ wsW,
    const float2* __restrict__ wsB, float* __restrict__ out) {
  const int bid = blockIdx.x;
  const int tid = threadIdx.x;
  if (bid >= 256) {
    zero_fill_slab(out, NF0 + (bid - 256), tid);
    return;
  }
  __shared__ float XR[17][128], XI[17][128];
  __shared__ float TR[32][128], TI[32][128];
  __shared__ float Rc[256], Rs[256];
  for (int i = tid; i < 256; i += TPB) {
    float sv, cv; sincosf(6.283185307179586f * (float)i / 256.0f, &sv, &cv);
    Rc[i] = cv; Rs[i] = sv;
  }
  __syncthreads();

  const int b = bid >> 5;
  const int ha = bid & 31;
  const int h = (ha < 16) ? ha : (224 + ha);
  const float* src = x + ((size_t)(b * 256 + h)) * 32768;
  // TR/TI rows 0..16 double as the forward reduction scratch.
  forward_slab(src, XR, XI, (float(*)[128])TR, (float(*)[128])TI, Rc, Rs, tid);

  // phase C: Z = X*Wft + Bft, alpha weights, zero k>64, bit-reversed into TR/TI.
  for (int u = tid; u < 32 * 128; u += TPB) {
    const int fi = u >> 7, k = u & 127;
    float gr = 0.f, gi = 0.f;
    if (k <= 64) {
      const int f = fi - 16;
      float xr, xi;
      if (f >= 0) { const int p = br7(k); xr = XR[f][p]; xi = XI[f][p]; }
      else { const int kk = (128 - k) & 127; const int p = br7(kk);
             xr = XR[-f][p]; xi = -XI[-f][p]; }
      const float2 wf = wsW[(ha * 32 + fi) * 65 + k];
      const float2 bf = wsB[(ha * 32 + fi) * 65 + k];
      gr = xr * wf.x - xi * wf.y + bf.x;
      gi = xr * wf.y + xi * wf.x + bf.y;
      const float al = (k == 0 || k == 64) ? 1.f : 2.f;
      gr *= al; gi *= al;
    }
    const int p = br7(k);
    TR[fi][p] = gr; TI[fi][p] = gi;
  }
  __syncthreads();

  // phase D: t[f,c] = sum_k G[f,k] e^{+2pi i k c/128}; 32 rows, DIT sign +.
  for (int s = 0; s <= 6; ++s) {
    const int L = 1 << s;
    for (int u = tid; u < 32 * 64; u += TPB) {
      const int row = u >> 6, qq = u & 63;
      const int jj = qq & (L - 1);
      const int pos = ((qq >> s) << (s + 1)) | jj;
      const int ti = jj << (7 - s);
      const float tc = Rc[ti], ts = Rs[ti];
      const float b0r = TR[row][pos + L], b0i = TI[row][pos + L];
      const float pr = b0r * tc - b0i * ts;
      const float pi = fmaf(b0r, ts, b0i * tc);
      const float a0r = TR[row][pos], a0i = TI[row][pos];
      TR[row][pos + L] = a0r - pr; TI[row][pos + L] = a0i - pi;
      TR[row][pos]     = a0r + pr; TI[row][pos]     = a0i + pi;
    }
    __syncthreads();
  }

  // phase E: out[16*w1+w0, c] = (1/32768) * Re( sum_g U[g] e^{+2pi i g w1/16} )
  const int c = tid & 127;
  const int q = tid >> 7;          // 0..3
  constexpr int BR4[16] = {0, 8, 4, 12, 2, 10, 6, 14, 1, 9, 5, 13, 3, 11, 7, 15};
  const float inv = 1.0f / 32768.0f;
  float* og = out + ((size_t)(b * 256 + h)) * 32768;

  #pragma unroll 1
  for (int it = 0; it < 4; ++it) {
    const int w0 = q + it * 4;     // wave-uniform
    float Ur[16], Ui[16];
    #pragma unroll
    for (int g = 0; g < 16; ++g) {
      const int gb = BR4[g];            // load bit-reversed for DIT
      const float t1r = TR[gb + 16][c], t1i = TI[gb + 16][c];  // f = gb
      const float t0r = TR[gb][c],      t0i = TI[gb][c];       // f = gb-16
      const int i1 = (gb * w0) & 255;
      const int i2 = ((gb - 16) * w0) & 255;
      const float c1 = Rc[i1], s1 = Rs[i1];   // e^{+i theta}
      const float c2 = Rc[i2], s2 = Rs[i2];
      Ur[g] = t1r * c1 - t1i * s1 + t0r * c2 - t0i * s2;
      Ui[g] = t1r * s1 + t1i * c1 + t0r * s2 + t0i * c2;
    }
    fft16_pos(Ur, Ui);
    #pragma unroll
    for (int w1 = 0; w1 < 16; ++w1)
      og[(w1 * 16 + w0) * 128 + c] = Ur[w1] * inv;
  }
}

extern "C" void kernel_launch(void* const* d_in, const int* in_sizes, int n_in,
                              void* d_out, int out_size, void* d_ws, size_t ws_size,
                              hipStream_t stream) {
  const float* x = (const float*)d_in[0];
  const float* w = (const float*)d_in[1];
  const float* b = (const float*)d_in[2];
  float* out = (float*)d_out;
  float2* wsW = (float2*)d_ws;
  float2* wsB = wsW + 32 * 32 * 65;   // 66560 float2 each (532,480 B)

  hipLaunchKernelGGL(k0_wft_and_fill, dim3(64 + NF0), dim3(TPB), 0, stream,
                     w, b, wsW, wsB, out);
  hipLaunchKernelGGL(fourier_active, dim3(256 + NF2), dim3(TPB), 0, stream,
                     x, wsW, wsB, out);
}